// Round 1
// baseline (201.703 us; speedup 1.0000x reference)
//
#include <hip/hip_runtime.h>

#define B_ 32
#define C_ 512
#define HW_ 4096
#define N_ 80

typedef __bf16 bf16x8 __attribute__((ext_vector_type(8)));
typedef float f32x4 __attribute__((ext_vector_type(4)));
typedef unsigned short u16x8 __attribute__((ext_vector_type(8)));
typedef unsigned short u16x4 __attribute__((ext_vector_type(4)));

__device__ __forceinline__ unsigned short f2bf(float x) {
  unsigned u = __builtin_bit_cast(unsigned, x);
  u += 0x7FFFu + ((u >> 16) & 1u);   // round-to-nearest-even (finite inputs)
  return (unsigned short)(u >> 16);
}
__device__ __forceinline__ float bf2f(unsigned short h) {
  unsigned u = ((unsigned)h) << 16;
  return __builtin_bit_cast(float, u);
}
__device__ __forceinline__ bf16x8 pack8(float a0, float a1, float a2, float a3,
                                        float a4, float a5, float a6, float a7) {
  u16x8 t;
  t[0] = f2bf(a0); t[1] = f2bf(a1); t[2] = f2bf(a2); t[3] = f2bf(a3);
  t[4] = f2bf(a4); t[5] = f2bf(a5); t[6] = f2bf(a6); t[7] = f2bf(a7);
  return __builtin_bit_cast(bf16x8, t);
}

// ---------------------------------------------------------------------------
// K1: logits[b][n][h] (bf16) = sum_c feats[b][c][h] * W[n][c]
// MFMA view per b: D[h][n], A[h][c] = feats^T (8 c-strided scalar loads/frag),
// B[c][n] = W rows (K-contiguous float4 loads). No LDS.
// Block: 256 thr = 4 waves; wave owns [32 h][80 n]; grid (HW/128, B).
// ---------------------------------------------------------------------------
__global__ __launch_bounds__(256) void k1_logits(const float* __restrict__ feats,
                                                 const float* __restrict__ Wm,
                                                 unsigned short* __restrict__ logits) {
  const int tid = threadIdx.x;
  const int lane = tid & 63, wave = tid >> 6;
  const int quad = lane >> 4, l16 = lane & 15;
  const int b = blockIdx.y;
  const int htile = blockIdx.x * 128 + wave * 32;
  const float* fb = feats + (size_t)b * C_ * HW_;

  const f32x4 zero = {0.f, 0.f, 0.f, 0.f};
  f32x4 acc[2][5];
#pragma unroll
  for (int hf = 0; hf < 2; ++hf)
#pragma unroll
    for (int nf = 0; nf < 5; ++nf) acc[hf][nf] = zero;

  for (int c0 = 0; c0 < C_; c0 += 32) {
    const int cb = c0 + quad * 8;  // lane's K-chunk base (c)
    bf16x8 afr[2];
#pragma unroll
    for (int hf = 0; hf < 2; ++hf) {
      const float* ap = fb + (size_t)cb * HW_ + htile + hf * 16 + l16;
      float v[8];
#pragma unroll
      for (int i = 0; i < 8; ++i) v[i] = ap[(size_t)i * HW_];
      afr[hf] = pack8(v[0], v[1], v[2], v[3], v[4], v[5], v[6], v[7]);
    }
#pragma unroll
    for (int nf = 0; nf < 5; ++nf) {
      const float* wp = Wm + (size_t)(nf * 16 + l16) * C_ + cb;
      const float4 w0 = *(const float4*)(wp);
      const float4 w1 = *(const float4*)(wp + 4);
      const bf16x8 bfr = pack8(w0.x, w0.y, w0.z, w0.w, w1.x, w1.y, w1.z, w1.w);
#pragma unroll
      for (int hf = 0; hf < 2; ++hf)
        acc[hf][nf] =
            __builtin_amdgcn_mfma_f32_16x16x32_bf16(afr[hf], bfr, acc[hf][nf], 0, 0, 0);
    }
  }
  // D: row(h) = quad*4 + j, col(n) = l16 -> 4 consecutive h per lane = 8B store
#pragma unroll
  for (int nf = 0; nf < 5; ++nf) {
    const int n = nf * 16 + l16;
#pragma unroll
    for (int hf = 0; hf < 2; ++hf) {
      const int h = htile + hf * 16 + quad * 4;
      u16x4 pk;
#pragma unroll
      for (int j = 0; j < 4; ++j) pk[j] = f2bf(acc[hf][nf][j]);
      *(u16x4*)(logits + (size_t)(b * N_ + n) * HW_ + h) = pk;
    }
  }
}

// ---------------------------------------------------------------------------
// K2: in-place row softmax over h. One block per (b,n) row; 256 thr x 16 elems.
// ---------------------------------------------------------------------------
__global__ __launch_bounds__(256) void k2_softmax(unsigned short* __restrict__ att) {
  const int tid = threadIdx.x;
  const int lane = tid & 63, wave = tid >> 6;
  unsigned short* rp = att + (size_t)blockIdx.x * HW_ + tid * 16;
  const u16x8 v0 = *(const u16x8*)(rp);
  const u16x8 v1 = *(const u16x8*)(rp + 8);
  float x[16];
#pragma unroll
  for (int i = 0; i < 8; ++i) { x[i] = bf2f(v0[i]); x[i + 8] = bf2f(v1[i]); }

  float m = x[0];
#pragma unroll
  for (int i = 1; i < 16; ++i) m = fmaxf(m, x[i]);
#pragma unroll
  for (int off = 32; off >= 1; off >>= 1) m = fmaxf(m, __shfl_xor(m, off));

  __shared__ float red[4];
  if (lane == 0) red[wave] = m;
  __syncthreads();
  m = fmaxf(fmaxf(red[0], red[1]), fmaxf(red[2], red[3]));

  float e[16];
  float s = 0.f;
#pragma unroll
  for (int i = 0; i < 16; ++i) { e[i] = __expf(x[i] - m); s += e[i]; }
#pragma unroll
  for (int off = 32; off >= 1; off >>= 1) s += __shfl_xor(s, off);
  __syncthreads();
  if (lane == 0) red[wave] = s;
  __syncthreads();
  s = red[0] + red[1] + red[2] + red[3];
  const float r = 1.0f / s;

  u16x8 o0, o1;
#pragma unroll
  for (int i = 0; i < 8; ++i) { o0[i] = f2bf(e[i] * r); o1[i] = f2bf(e[i + 8] * r); }
  *(u16x8*)(rp) = o0;
  *(u16x8*)(rp + 8) = o1;
}

// ---------------------------------------------------------------------------
// K3: out[b][n][c] = sum_h att[b][n][h] * feats[b][c][h]
// MFMA view: D[c][n] = sum_h A[c][h]*B[h][n]; A = feats rows (float4 pairs),
// B = att rows (bf16 ushort8, no conversion). D writes aligned float4 to out.
// Block: 4 waves x [16 c][80 n]; grid (C/64, B).
// ---------------------------------------------------------------------------
__global__ __launch_bounds__(256) void k3_pool(const float* __restrict__ feats,
                                               const unsigned short* __restrict__ att,
                                               float* __restrict__ out) {
  const int tid = threadIdx.x;
  const int lane = tid & 63, wave = tid >> 6;
  const int quad = lane >> 4, l16 = lane & 15;
  const int b = blockIdx.y;
  const int c0 = blockIdx.x * 64 + wave * 16;
  const float* fb = feats + (size_t)b * C_ * HW_ + (size_t)(c0 + l16) * HW_;
  const unsigned short* ab = att + (size_t)b * N_ * HW_;

  const f32x4 zero = {0.f, 0.f, 0.f, 0.f};
  f32x4 acc[5];
#pragma unroll
  for (int nf = 0; nf < 5; ++nf) acc[nf] = zero;

  for (int h0 = 0; h0 < HW_; h0 += 32) {
    const int hk = h0 + quad * 8;  // lane's K-chunk base (h)
    const float4 a0 = *(const float4*)(fb + hk);
    const float4 a1 = *(const float4*)(fb + hk + 4);
    const bf16x8 af = pack8(a0.x, a0.y, a0.z, a0.w, a1.x, a1.y, a1.z, a1.w);
#pragma unroll
    for (int nf = 0; nf < 5; ++nf) {
      const u16x8 bv = *(const u16x8*)(ab + (size_t)(nf * 16 + l16) * HW_ + hk);
      const bf16x8 bfr = __builtin_bit_cast(bf16x8, bv);
      acc[nf] = __builtin_amdgcn_mfma_f32_16x16x32_bf16(af, bfr, acc[nf], 0, 0, 0);
    }
  }
  // D: row(c) = quad*4 + j, col(n) = l16 -> 4 consecutive c = aligned float4
#pragma unroll
  for (int nf = 0; nf < 5; ++nf) {
    const int n = nf * 16 + l16;
    float4 v;
    v.x = acc[nf][0]; v.y = acc[nf][1]; v.z = acc[nf][2]; v.w = acc[nf][3];
    *(float4*)(out + (size_t)(b * N_ + n) * C_ + c0 + quad * 4) = v;
  }
}

extern "C" void kernel_launch(void* const* d_in, const int* in_sizes, int n_in,
                              void* d_out, int out_size, void* d_ws, size_t ws_size,
                              hipStream_t stream) {
  (void)in_sizes; (void)n_in; (void)out_size; (void)ws_size;
  const float* feats = (const float*)d_in[0];
  const float* Wm = (const float*)d_in[1];
  float* out = (float*)d_out;
  unsigned short* att = (unsigned short*)d_ws;  // 32*80*4096 bf16 = 21 MB

  hipLaunchKernelGGL(k1_logits, dim3(HW_ / 128, B_), dim3(256), 0, stream, feats, Wm, att);
  hipLaunchKernelGGL(k2_softmax, dim3(B_ * N_), dim3(256), 0, stream, att);
  hipLaunchKernelGGL(k3_pool, dim3(C_ / 64, B_), dim3(256), 0, stream, feats, att, out);
}

// Round 2
// 190.747 us; speedup vs baseline: 1.0574x; 1.0574x over previous
//
#include <hip/hip_runtime.h>

#define B_ 32
#define C_ 512
#define HW_ 4096
#define N_ 80

typedef __bf16 bf16x8 __attribute__((ext_vector_type(8)));
typedef __bf16 bf16x4 __attribute__((ext_vector_type(4)));
typedef float f32x4 __attribute__((ext_vector_type(4)));
typedef unsigned short u16x8 __attribute__((ext_vector_type(8)));

// ---------------------------------------------------------------------------
// K0: one-time W f32 -> bf16 (80x512 = 40960 elems)
// ---------------------------------------------------------------------------
__global__ __launch_bounds__(256) void k0_wconv(const float* __restrict__ W,
                                                __bf16* __restrict__ Wbf) {
  const int i = blockIdx.x * 256 + threadIdx.x;
  if (i < N_ * C_) Wbf[i] = (__bf16)W[i];
}

// ---------------------------------------------------------------------------
// K1: logits[b][n][h] (bf16) = sum_c feats[b][c][h] * W[n][c]
// MFMA D[h][n]: A[h][c]=feats^T (8 c-strided scalar loads/frag, native casts),
// B[c][n]=Wbf rows (direct u16x8, no conversion). No LDS.
// Block: 4 waves; wave owns [32 h][80 n]; grid (HW/128, B).
// ---------------------------------------------------------------------------
__global__ __launch_bounds__(256) void k1_logits(const float* __restrict__ feats,
                                                 const __bf16* __restrict__ Wbf,
                                                 __bf16* __restrict__ logits) {
  const int tid = threadIdx.x;
  const int lane = tid & 63, wave = tid >> 6;
  const int quad = lane >> 4, l16 = lane & 15;
  const int b = blockIdx.y;
  const int htile = blockIdx.x * 128 + wave * 32;
  const float* fb = feats + (size_t)b * (C_ * HW_);

  const f32x4 zero = {0.f, 0.f, 0.f, 0.f};
  f32x4 acc[2][5];
#pragma unroll
  for (int hf = 0; hf < 2; ++hf)
#pragma unroll
    for (int nf = 0; nf < 5; ++nf) acc[hf][nf] = zero;

  // A base (elements, 32-bit): row = quad*8 + i, col = htile + hf*16 + l16
  const unsigned abase = (unsigned)(quad * 8) * HW_ + (unsigned)(htile + l16);

  for (int c0 = 0; c0 < C_; c0 += 32) {
    bf16x8 afr[2];
#pragma unroll
    for (int hf = 0; hf < 2; ++hf) {
      const unsigned off = abase + (unsigned)c0 * HW_ + (unsigned)(hf * 16);
      float v[8];
#pragma unroll
      for (int i = 0; i < 8; ++i) v[i] = fb[off + (unsigned)i * HW_];
      bf16x8 a;
#pragma unroll
      for (int i = 0; i < 8; ++i) a[i] = (__bf16)v[i];
      afr[hf] = a;
    }
#pragma unroll
    for (int nf = 0; nf < 5; ++nf) {
      const u16x8 bv =
          *(const u16x8*)(Wbf + (unsigned)(nf * 16 + l16) * C_ + (unsigned)(c0 + quad * 8));
      const bf16x8 bfr = __builtin_bit_cast(bf16x8, bv);
#pragma unroll
      for (int hf = 0; hf < 2; ++hf)
        acc[hf][nf] =
            __builtin_amdgcn_mfma_f32_16x16x32_bf16(afr[hf], bfr, acc[hf][nf], 0, 0, 0);
    }
  }
  // D: row(h) = quad*4 + j, col(n) = l16 -> 4 consecutive h per lane = 8B store
#pragma unroll
  for (int nf = 0; nf < 5; ++nf) {
    const int n = nf * 16 + l16;
#pragma unroll
    for (int hf = 0; hf < 2; ++hf) {
      const int h = htile + hf * 16 + quad * 4;
      bf16x4 pk;
#pragma unroll
      for (int j = 0; j < 4; ++j) pk[j] = (__bf16)acc[hf][nf][j];
      *(bf16x4*)(logits + (size_t)(b * N_ + n) * HW_ + h) = pk;
    }
  }
}

// ---------------------------------------------------------------------------
// K2: in-place row softmax over h. One block per (b,n) row; 256 thr x 16 elems.
// ---------------------------------------------------------------------------
__global__ __launch_bounds__(256) void k2_softmax(__bf16* __restrict__ att) {
  const int tid = threadIdx.x;
  const int lane = tid & 63, wave = tid >> 6;
  __bf16* rp = att + (size_t)blockIdx.x * HW_ + tid * 16;
  const bf16x8 v0 = *(const bf16x8*)(rp);
  const bf16x8 v1 = *(const bf16x8*)(rp + 8);
  float x[16];
#pragma unroll
  for (int i = 0; i < 8; ++i) { x[i] = (float)v0[i]; x[i + 8] = (float)v1[i]; }

  float m = x[0];
#pragma unroll
  for (int i = 1; i < 16; ++i) m = fmaxf(m, x[i]);
#pragma unroll
  for (int off = 32; off >= 1; off >>= 1) m = fmaxf(m, __shfl_xor(m, off));

  __shared__ float red[4];
  if (lane == 0) red[wave] = m;
  __syncthreads();
  m = fmaxf(fmaxf(red[0], red[1]), fmaxf(red[2], red[3]));

  float e[16];
  float s = 0.f;
#pragma unroll
  for (int i = 0; i < 16; ++i) { e[i] = __expf(x[i] - m); s += e[i]; }
#pragma unroll
  for (int off = 32; off >= 1; off >>= 1) s += __shfl_xor(s, off);
  __syncthreads();
  if (lane == 0) red[wave] = s;
  __syncthreads();
  s = red[0] + red[1] + red[2] + red[3];
  const float r = 1.0f / s;

  bf16x8 o0, o1;
#pragma unroll
  for (int i = 0; i < 8; ++i) {
    o0[i] = (__bf16)(e[i] * r);
    o1[i] = (__bf16)(e[i + 8] * r);
  }
  *(bf16x8*)(rp) = o0;
  *(bf16x8*)(rp + 8) = o1;
}

// ---------------------------------------------------------------------------
// K3: out[b][n][c] = sum_h att[b][n][h] * feats[b][c][h]
// MFMA D[c][n]: A = feats rows (float4 pairs, native casts), B = att rows
// (direct u16x8). D writes aligned float4. Block: 4 waves; grid (C/64, B).
// ---------------------------------------------------------------------------
__global__ __launch_bounds__(256) void k3_pool(const float* __restrict__ feats,
                                               const __bf16* __restrict__ att,
                                               float* __restrict__ out) {
  const int tid = threadIdx.x;
  const int lane = tid & 63, wave = tid >> 6;
  const int quad = lane >> 4, l16 = lane & 15;
  const int b = blockIdx.y;
  const int c0 = blockIdx.x * 64 + wave * 16;
  const float* fb = feats + (size_t)b * (C_ * HW_);
  const __bf16* ab = att + (size_t)b * N_ * HW_;
  const unsigned arow = (unsigned)(c0 + l16) * HW_;

  const f32x4 zero = {0.f, 0.f, 0.f, 0.f};
  f32x4 acc[5];
#pragma unroll
  for (int nf = 0; nf < 5; ++nf) acc[nf] = zero;

  for (int h0 = 0; h0 < HW_; h0 += 32) {
    const unsigned hk = (unsigned)(h0 + quad * 8);
    const float4 a0 = *(const float4*)(fb + arow + hk);
    const float4 a1 = *(const float4*)(fb + arow + hk + 4);
    bf16x8 af;
    af[0] = (__bf16)a0.x; af[1] = (__bf16)a0.y; af[2] = (__bf16)a0.z; af[3] = (__bf16)a0.w;
    af[4] = (__bf16)a1.x; af[5] = (__bf16)a1.y; af[6] = (__bf16)a1.z; af[7] = (__bf16)a1.w;
#pragma unroll
    for (int nf = 0; nf < 5; ++nf) {
      const u16x8 bv = *(const u16x8*)(ab + (unsigned)(nf * 16 + l16) * HW_ + hk);
      const bf16x8 bfr = __builtin_bit_cast(bf16x8, bv);
      acc[nf] = __builtin_amdgcn_mfma_f32_16x16x32_bf16(af, bfr, acc[nf], 0, 0, 0);
    }
  }
  // D: row(c) = quad*4 + j, col(n) = l16 -> 4 consecutive c = aligned float4
#pragma unroll
  for (int nf = 0; nf < 5; ++nf) {
    const int n = nf * 16 + l16;
    float4 v;
    v.x = acc[nf][0]; v.y = acc[nf][1]; v.z = acc[nf][2]; v.w = acc[nf][3];
    *(float4*)(out + (size_t)(b * N_ + n) * C_ + c0 + quad * 4) = v;
  }
}

extern "C" void kernel_launch(void* const* d_in, const int* in_sizes, int n_in,
                              void* d_out, int out_size, void* d_ws, size_t ws_size,
                              hipStream_t stream) {
  (void)in_sizes; (void)n_in; (void)out_size; (void)ws_size;
  const float* feats = (const float*)d_in[0];
  const float* Wm = (const float*)d_in[1];
  float* out = (float*)d_out;
  __bf16* att = (__bf16*)d_ws;                       // 32*80*4096 bf16 = 21 MB
  __bf16* Wbf = (__bf16*)d_ws + (size_t)B_ * N_ * HW_;  // 80 KB, 16B-aligned

  hipLaunchKernelGGL(k0_wconv, dim3((N_ * C_ + 255) / 256), dim3(256), 0, stream, Wm, Wbf);
  hipLaunchKernelGGL(k1_logits, dim3(HW_ / 128, B_), dim3(256), 0, stream, feats, Wbf, att);
  hipLaunchKernelGGL(k2_softmax, dim3(B_ * N_), dim3(256), 0, stream, att);
  hipLaunchKernelGGL(k3_pool, dim3(C_ / 64, B_), dim3(256), 0, stream, feats, att, out);
}